// Round 11
// baseline (2006.635 us; speedup 1.0000x reference)
//
#include <hip/hip_runtime.h>

typedef float v2f __attribute__((ext_vector_type(2)));
typedef unsigned uv2 __attribute__((ext_vector_type(2)));

constexpr int NX = 32, NU = 16, NF = 512;
constexpr int SEQ = 2048;
constexpr int NT = 256;           // 1 row/block; 2 features/thread end-to-end
constexpr float SC  = 2.88539008177792681f;  // 2/ln2: tanh(a) = 1 - 2/(exp2(SC*a)+1)
constexpr float TSC = 0.01f;

// DPP partner read (VALU pipe). 0xB1 xor1 | 0x4E xor2 | 0x128 row_ror:8 (=xor8 in 16)
template<int CTRL>
__device__ __forceinline__ float dpp_mov(float v) {
    return __int_as_float(__builtin_amdgcn_update_dpp(0, __float_as_int(v), CTRL, 0xF, 0xF, true));
}
// gfx950 permlane swaps (VALU pipe): return v[l] + v[l^16] / v[l^32]
__device__ __forceinline__ float sum16(float v) {
    uv2 r = __builtin_amdgcn_permlane16_swap(__float_as_uint(v), __float_as_uint(v), false, false);
    return __uint_as_float(r.x) + __uint_as_float(r.y);
}
__device__ __forceinline__ float sum32(float v) {
    uv2 r = __builtin_amdgcn_permlane32_swap(__float_as_uint(v), __float_as_uint(v), false, false);
    return __uint_as_float(r.x) + __uint_as_float(r.y);
}

__device__ __forceinline__ float tanh4(float y) {       // y pre-scaled by SC
    const float e = __builtin_amdgcn_exp2f(y);
    const float r = __builtin_amdgcn_rcpf(e + 1.f);
    return fmaf(-2.f, r, 1.f);
}

__global__ __launch_bounds__(NT)
__attribute__((amdgpu_waves_per_eu(2, 2)))   // 256-reg budget, 2 waves/SIMD
void fes_kernel(const float* __restrict__ x0, const float* __restrict__ ug,
                const float* __restrict__ W1, const float* __restrict__ b1,
                const float* __restrict__ W2, const float* __restrict__ b2,
                float* __restrict__ out)
{
    __shared__ float part[2][8][33];      // ping-pong; [slot][j], pad 33: conflict-free

    const int tid = threadIdx.x, row = blockIdx.x;
    const int l = tid & 63, w = tid >> 6;

    // lane -> owned output j (XOR-linear): pi(1)=16, pi(2)=8, pi(8)=4, pi(16)=2, pi(32)=1, pi(4)=0
    const int pi = ((l & 1) << 4) | (((l >> 1) & 1) << 3) | (((l >> 3) & 1) << 2)
                 | (((l >> 4) & 1) << 1) | ((l >> 5) & 1);
    const int slot = w * 2 + ((l >> 2) & 1);        // 8 partials per j
    const bool store_lane = (w == 0) && ((l & 4) == 0);

    const int f0 = 2 * tid, f1 = f0 + 1;            // this thread's two features

    // ---- persistent registers --------------------------------------------
    // G1 x-part weights, paired to the gather order: pair m <-> x indices (pi^2m, pi^(2m+1))
    v2f wxA[16], wxB[16];
#pragma unroll
    for (int m = 0; m < 16; ++m) {
        const int ja = pi ^ (2 * m), jb = pi ^ (2 * m + 1);
        wxA[m] = v2f{SC * W1[ja * NF + f0], SC * W1[jb * NF + f0]};
        wxB[m] = v2f{SC * W1[ja * NF + f1], SC * W1[jb * NF + f1]};
    }
    // G1 u-part weights, canonical order (u regs are canonical)
    v2f wuA[8], wuB[8];
#pragma unroll
    for (int p = 0; p < 8; ++p) {
        const int k = NX + 2 * p;
        wuA[p] = v2f{SC * W1[k * NF + f0], SC * W1[(k + 1) * NF + f0]};
        wuB[p] = v2f{SC * W1[k * NF + f1], SC * W1[(k + 1) * NF + f1]};
    }
    const float b1A = SC * b1[f0], b1B = SC * b1[f1];

    // G2 weights, pi-domain: position p holds j = p ^ pi
    v2f wcA[16], wcB[16];
#pragma unroll
    for (int m = 0; m < 16; ++m) {
        wcA[m] = v2f{TSC * W2[f0 * NX + ((2 * m) ^ pi)], TSC * W2[f0 * NX + ((2 * m + 1) ^ pi)]};
        wcB[m] = v2f{TSC * W2[f1 * NX + ((2 * m) ^ pi)], TSC * W2[f1 * NX + ((2 * m + 1) ^ pi)]};
    }
    const float bb = TSC * b2[pi];

    // x state in registers, gather order: xg[r] = x[pi ^ r]
    float xg[32];
#pragma unroll
    for (int r = 0; r < 32; ++r) xg[r] = x0[row * NX + (pi ^ r)];

    const float* ug_row  = ug  + (size_t)row * SEQ * NU;
    float*       out_row = out + (size_t)row * SEQ * NX;

#pragma unroll 1
    for (int t = 0; t < SEQ; ++t) {
        // ---- issue u loads early (L1/L2-hit; consumed after x-part) ------
        const float* up = ug_row + (size_t)t * NU;
        const float4 u0 = *(const float4*)(up + 0);
        const float4 u1 = *(const float4*)(up + 4);
        const float4 u2 = *(const float4*)(up + 8);
        const float4 u3 = *(const float4*)(up + 12);

        // ---- G1: x-part from registers (permuted order matches weights) --
        v2f aA0 = {b1A, 0.f}, aA1 = {0.f, 0.f};
        v2f aB0 = {b1B, 0.f}, aB1 = {0.f, 0.f};
#pragma unroll
        for (int m = 0; m < 16; ++m) {
            const v2f xv = {xg[2 * m], xg[2 * m + 1]};
            if (m & 1) { aA1 += wxA[m] * xv; aB1 += wxB[m] * xv; }
            else       { aA0 += wxA[m] * xv; aB0 += wxB[m] * xv; }
        }
        // ---- G1: u-part --------------------------------------------------
#define UPAIR(uv, p)                                                        \
        { const v2f lo = {uv.x, uv.y}, hi = {uv.z, uv.w};                   \
          aA0 += wuA[p] * lo;  aA1 += wuA[p + 1] * hi;                      \
          aB0 += wuB[p] * lo;  aB1 += wuB[p + 1] * hi; }
        UPAIR(u0, 0) UPAIR(u1, 2) UPAIR(u2, 4) UPAIR(u3, 6)
#undef UPAIR
        const float h0 = tanh4((aA0.x + aA0.y) + (aA1.x + aA1.y));
        const float h1 = tanh4((aB0.x + aB0.y) + (aB1.x + aB1.y));

        // ---- G2: pi-domain partials (32 pk-fma) --------------------------
        const v2f h0v = {h0, h0}, h1v = {h1, h1};
        v2f q[16];
#pragma unroll
        for (int m = 0; m < 16; ++m)
            q[m] = h0v * wcA[m] + h1v * wcB[m];

        // ---- in-wave reduce-scatter: all VALU-pipe -----------------------
#pragma unroll
        for (int m = 0; m < 8; ++m) {                 // d=1 (j-bit 16)
            q[m].x += dpp_mov<0xB1>(q[m + 8].x);
            q[m].y += dpp_mov<0xB1>(q[m + 8].y);
        }
#pragma unroll
        for (int m = 0; m < 4; ++m) {                 // d=2 (j-bit 8)
            q[m].x += dpp_mov<0x4E>(q[m + 4].x);
            q[m].y += dpp_mov<0x4E>(q[m + 4].y);
        }
#pragma unroll
        for (int m = 0; m < 2; ++m) {                 // d=8 (j-bit 4)
            q[m].x += dpp_mov<0x128>(q[m + 2].x);
            q[m].y += dpp_mov<0x128>(q[m + 2].y);
        }
        // d=16 (j-bit 2): partner = sum16 - self (convention-independent)
        const float S0 = q[0].x + (sum16(q[1].x) - q[1].x);
        const float S1 = q[0].y + (sum16(q[1].y) - q[1].y);
        // d=32 (j-bit 1)
        const float S = S0 + (sum32(S1) - S1);
        // d=4 contributes nothing (pi(4)=0): lanes l, l^4 hold coset partials -> both written

        // ---- cross-wave combine: 1 write, 1 barrier, 8 b32 reads ---------
        part[t & 1][slot][pi] = S;
        __syncthreads();
        const float* pb = &part[t & 1][0][pi];
        const float p0 = pb[0],   p1 = pb[33],  p2 = pb[66],  p3 = pb[99];
        const float p4 = pb[132], p5 = pb[165], p6 = pb[198], p7 = pb[231];
        const float dx = (((p0 + p1) + (p2 + p3)) + ((p4 + p5) + (p6 + p7))) + bb;
        const float xn = xg[0] + dx;                  // xg[0] = own x[pi]
        if (store_lane) out_row[(size_t)t * NX + pi] = xn;

        // ---- all-gather xn -> xg (5 VALU levels, no LDS) -----------------
        xg[0] = xn;
        xg[1] = sum32(xg[0]) - xg[0];                 // j-bit 0
        xg[2] = sum16(xg[0]) - xg[0];                 // j-bit 1
        xg[3] = sum16(xg[1]) - xg[1];
#pragma unroll
        for (int r = 0; r < 4; ++r)  xg[4 + r]  = dpp_mov<0x128>(xg[r]);   // j-bit 2
#pragma unroll
        for (int r = 0; r < 8; ++r)  xg[8 + r]  = dpp_mov<0x4E>(xg[r]);    // j-bit 3
#pragma unroll
        for (int r = 0; r < 16; ++r) xg[16 + r] = dpp_mov<0xB1>(xg[r]);    // j-bit 4
    }
}

extern "C" void kernel_launch(void* const* d_in, const int* in_sizes, int n_in,
                              void* d_out, int out_size, void* d_ws, size_t ws_size,
                              hipStream_t stream) {
    const float* x0 = (const float*)d_in[0];
    const float* ug = (const float*)d_in[1];
    const float* W1 = (const float*)d_in[2];
    const float* b1 = (const float*)d_in[3];
    const float* W2 = (const float*)d_in[4];
    const float* b2 = (const float*)d_in[5];
    float* out = (float*)d_out;

    fes_kernel<<<dim3(512), dim3(NT), 0, stream>>>(x0, ug, W1, b1, W2, b2, out);
}

// Round 12
// 1741.833 us; speedup vs baseline: 1.1520x; 1.1520x over previous
//
#include <hip/hip_runtime.h>

typedef float v2f __attribute__((ext_vector_type(2)));
typedef unsigned uv2 __attribute__((ext_vector_type(2)));

constexpr int NX = 32, NU = 16, NF = 512;
constexpr int SEQ = 2048;
constexpr int NT = 256;           // 1 row/block; 2 features/thread end-to-end
constexpr float SC  = 2.88539008177792681f;  // 2/ln2: tanh(a) = 1 - 2/(exp2(SC*a)+1)
constexpr float TSC = 0.01f;

// DPP partner read (VALU pipe). 0xB1 xor1 | 0x4E xor2 | 0x128 row_ror:8 (=xor8 in 16)
template<int CTRL>
__device__ __forceinline__ float dpp_mov(float v) {
    return __int_as_float(__builtin_amdgcn_update_dpp(0, __float_as_int(v), CTRL, 0xF, 0xF, true));
}
// gfx950 permlane swaps (VALU pipe): v[l] + v[l^16] / v[l^32]
__device__ __forceinline__ float sum16(float v) {
    uv2 r = __builtin_amdgcn_permlane16_swap(__float_as_uint(v), __float_as_uint(v), false, false);
    return __uint_as_float(r.x) + __uint_as_float(r.y);
}
__device__ __forceinline__ float sum32(float v) {
    uv2 r = __builtin_amdgcn_permlane32_swap(__float_as_uint(v), __float_as_uint(v), false, false);
    return __uint_as_float(r.x) + __uint_as_float(r.y);
}

__device__ __forceinline__ float tanh4(float y) {       // y pre-scaled by SC
    const float e = __builtin_amdgcn_exp2f(y);
    const float r = __builtin_amdgcn_rcpf(e + 1.f);
    return fmaf(-2.f, r, 1.f);
}

// Raw barrier: LDS visibility only (lgkmcnt(0)); NO vmcnt drain -> out-stores
// and u-prefetch stay in flight across the barrier.
__device__ __forceinline__ void bar_lds() {
    asm volatile("s_waitcnt lgkmcnt(0)" ::: "memory");
    __builtin_amdgcn_sched_barrier(0);
    __builtin_amdgcn_s_barrier();
    __builtin_amdgcn_sched_barrier(0);
    asm volatile("" ::: "memory");
}

__global__ __launch_bounds__(NT)
__attribute__((amdgpu_waves_per_eu(2, 2)))   // 256-reg budget, 2 waves/SIMD
void fes_kernel(const float* __restrict__ x0, const float* __restrict__ ug,
                const float* __restrict__ W1, const float* __restrict__ b1,
                const float* __restrict__ W2, const float* __restrict__ b2,
                float* __restrict__ out)
{
    __shared__ __align__(16) float xs_w[4][NX];     // per-wave private state copies
    __shared__ float part[2][8][33];                // ping-pong partials, pad 33: conflict-free

    const int tid = threadIdx.x, row = blockIdx.x;
    const int l = tid & 63, w = tid >> 6;

    // lane -> owned output j (XOR-linear): pi(1)=16, pi(2)=8, pi(8)=4, pi(16)=2, pi(32)=1, pi(4)=0
    const int pi = ((l & 1) << 4) | (((l >> 1) & 1) << 3) | (((l >> 3) & 1) << 2)
                 | (((l >> 4) & 1) << 1) | ((l >> 5) & 1);
    const int slot = w * 2 + ((l >> 2) & 1);        // 8 partials per j
    const bool jown = (l & 4) == 0;                 // one writer per j per wave
    const bool store_lane = (w == 0) && jown;

    const int f0 = 2 * tid, f1 = f0 + 1;            // this thread's two features

    // ---- persistent registers (round-10 proven maps) ---------------------
    v2f wkA[24], wkB[24];                           // G1 weights, k-parity pairs
#pragma unroll
    for (int p = 0; p < 24; ++p) {
        wkA[p] = v2f{SC * W1[(2 * p) * NF + f0], SC * W1[(2 * p + 1) * NF + f0]};
        wkB[p] = v2f{SC * W1[(2 * p) * NF + f1], SC * W1[(2 * p + 1) * NF + f1]};
    }
    const float b1A = SC * b1[f0], b1B = SC * b1[f1];

    v2f wcA[16], wcB[16];                           // G2 weights, pi-domain
#pragma unroll
    for (int m = 0; m < 16; ++m) {
        wcA[m] = v2f{TSC * W2[f0 * NX + ((2 * m) ^ pi)], TSC * W2[f0 * NX + ((2 * m + 1) ^ pi)]};
        wcB[m] = v2f{TSC * W2[f1 * NX + ((2 * m) ^ pi)], TSC * W2[f1 * NX + ((2 * m + 1) ^ pi)]};
    }
    const float bb = TSC * b2[pi];
    float xr = x0[row * NX + pi];                   // lane-resident state element

    const float* ug_row  = ug  + (size_t)row * SEQ * NU;
    float*       out_row = out + (size_t)row * SEQ * NX;

    if (jown) xs_w[w][pi] = xr;                     // wave-private: no barrier needed
    float4 u0 = *(const float4*)(ug_row + 0);
    float4 u1 = *(const float4*)(ug_row + 4);
    float4 u2 = *(const float4*)(ug_row + 8);
    float4 u3 = *(const float4*)(ug_row + 12);

    const float4* xsr = (const float4*)xs_w[w];

#pragma unroll 1
    for (int t = 0; t < SEQ; ++t) {
        // ---- G1: full 48-dots for f0, f1 (8 uniform b128 + reg u) --------
        v2f aA0 = {b1A, 0.f}, aA1 = {0.f, 0.f};
        v2f aB0 = {b1B, 0.f}, aB1 = {0.f, 0.f};
#pragma unroll
        for (int s = 0; s < 8; ++s) {
            const float4 iv = xsr[s];               // wave-uniform broadcast
            const v2f lo = {iv.x, iv.y}, hi = {iv.z, iv.w};
            aA0 += wkA[2 * s] * lo;  aA1 += wkA[2 * s + 1] * hi;
            aB0 += wkB[2 * s] * lo;  aB1 += wkB[2 * s + 1] * hi;
        }
#define UPART(uv, p0)                                                       \
        { const v2f lo = {uv.x, uv.y}, hi = {uv.z, uv.w};                   \
          aA0 += wkA[p0] * lo;  aA1 += wkA[p0 + 1] * hi;                    \
          aB0 += wkB[p0] * lo;  aB1 += wkB[p0 + 1] * hi; }
        UPART(u0, 16) UPART(u1, 18) UPART(u2, 20) UPART(u3, 22)
#undef UPART
        // prefetch next u (now genuinely overlaps the barrier: no vmcnt drain)
        {
            const int tn = (t + 1 < SEQ) ? t + 1 : SEQ - 1;
            const float* un = ug_row + (size_t)tn * NU;
            u0 = *(const float4*)(un + 0);
            u1 = *(const float4*)(un + 4);
            u2 = *(const float4*)(un + 8);
            u3 = *(const float4*)(un + 12);
        }
        const float h0 = tanh4((aA0.x + aA0.y) + (aA1.x + aA1.y));
        const float h1 = tanh4((aB0.x + aB0.y) + (aB1.x + aB1.y));

        // ---- G2: in-register, pi-permuted (32 pk-fma) --------------------
        const v2f h0v = {h0, h0}, h1v = {h1, h1};
        v2f q[16];
#pragma unroll
        for (int m = 0; m < 16; ++m)
            q[m] = h0v * wcA[m] + h1v * wcB[m];

        // ---- in-wave reduce-scatter: all VALU-pipe -----------------------
#pragma unroll
        for (int m = 0; m < 8; ++m) {                 // d=1 (j-bit 16)
            q[m].x += dpp_mov<0xB1>(q[m + 8].x);
            q[m].y += dpp_mov<0xB1>(q[m + 8].y);
        }
#pragma unroll
        for (int m = 0; m < 4; ++m) {                 // d=2 (j-bit 8)
            q[m].x += dpp_mov<0x4E>(q[m + 4].x);
            q[m].y += dpp_mov<0x4E>(q[m + 4].y);
        }
#pragma unroll
        for (int m = 0; m < 2; ++m) {                 // d=8 (j-bit 4)
            q[m].x += dpp_mov<0x128>(q[m + 2].x);
            q[m].y += dpp_mov<0x128>(q[m + 2].y);
        }
        // d=16 (j-bit 2): partner = sum16 - self (convention-independent)
        const float S0 = q[0].x + (sum16(q[1].x) - q[1].x);
        const float S1 = q[0].y + (sum16(q[1].y) - q[1].y);
        // d=32 (j-bit 1)
        const float S = S0 + (sum32(S1) - S1);
        // d=4 contributes nothing (pi(4)=0): both coset lanes write their partial

        // ---- cross-wave combine: 1 write, 1 raw barrier, 8 b32 reads -----
        part[t & 1][slot][pi] = S;
        bar_lds();
        const float* pb = &part[t & 1][0][pi];
        const float p0 = pb[0],   p1 = pb[33],  p2 = pb[66],  p3 = pb[99];
        const float p4 = pb[132], p5 = pb[165], p6 = pb[198], p7 = pb[231];
        const float dx = (((p0 + p1) + (p2 + p3)) + ((p4 + p5) + (p6 + p7))) + bb;
        const float xn = xr + dx;
        xr = xn;
        if (store_lane) out_row[(size_t)t * NX + pi] = xn;   // retires lazily
        if (jown) xs_w[w][pi] = xn;                 // own wave's copy (lgkm-ordered)
    }
}

extern "C" void kernel_launch(void* const* d_in, const int* in_sizes, int n_in,
                              void* d_out, int out_size, void* d_ws, size_t ws_size,
                              hipStream_t stream) {
    const float* x0 = (const float*)d_in[0];
    const float* ug = (const float*)d_in[1];
    const float* W1 = (const float*)d_in[2];
    const float* b1 = (const float*)d_in[3];
    const float* W2 = (const float*)d_in[4];
    const float* b2 = (const float*)d_in[5];
    float* out = (float*)d_out;

    fes_kernel<<<dim3(512), dim3(NT), 0, stream>>>(x0, ug, W1, b1, W2, b2, out);
}